// Round 5
// baseline (154.571 us; speedup 1.0000x reference)
//
#include <hip/hip_runtime.h>
#include <hip/hip_bf16.h>

// Problem constants
#define Bq 32
#define Lq 256
#define Hq 8
#define Eq 16
#define Nn (Bq*Hq)        // 256 sequences
#define T 254             // Lq - 3 + 1
#define A 145             // E + 1 + 128 augmented channels
#define SIG_CH (A + A*A)  // 21170
#define KP 21184          // padded K (mult of 32), bf16 arrays
#define OUT 256

typedef __attribute__((ext_vector_type(8))) short short8;
typedef __attribute__((ext_vector_type(8))) unsigned short ushort8;
typedef __attribute__((ext_vector_type(4))) float floatx4;

static __device__ __forceinline__ unsigned short f2bf(float v) {
    unsigned int u = __float_as_uint(v);
    unsigned int r = (u + 0x7FFFu + ((u >> 16) & 1u)) >> 16;
    return (unsigned short)r;
}
static __device__ __forceinline__ float bf2f(unsigned short b) {
    return __uint_as_float(((unsigned int)b) << 16);
}

// ---------------------------------------------------------------------------
// Kernel AS: FUSED aug+sig. 512 threads = 2 chunk pipelines per block
// (group g handles chunks {g, g+2, g+4, g+6}). a0 deferred via rank-1
// correction at fp32 epilogue.
// R4 lesson applied: q goes back through prefetch-regs -> xsc LDS (R2's
// proven form — direct global reads in the serial chain cost +2.7us).
// Conv weights stay in registers (wprep kernel deleted).
// ---------------------------------------------------------------------------
#define MDS 40    // M/D row stride (ushorts)
#define OS3 36    // outs row stride (floats)
#define XIS 72    // xim/a1 row stride (ushorts)
#define GRPB 61600 // per-group LDS bytes: 38400 (mdb) + 20880 (outs) + 2304 (xsc)
#define ACS 162   // accs row stride (floats)

__global__ __launch_bounds__(512) void augsig_kernel(
    const float* __restrict__ q,
    const float* __restrict__ b1, const float* __restrict__ b2,
    const float* __restrict__ w1, const float* __restrict__ w2,
    unsigned short* __restrict__ sig_hi, unsigned short* __restrict__ sig_lo)
{
    // 2*61600 + 256 (b1s) + 512 (b2s) + 640 (a0s) + 640 (vls) = 125248 B
    __shared__ __align__(16) char smem[2*GRPB + 256 + 512 + 640 + 640];

    const int tid512 = threadIdx.x;
    const int grp = tid512 >> 8;     // 0 or 1
    const int tid = tid512 & 255;    // local tid within group

    char* gb = smem + grp*GRPB;
    unsigned short* mdb = (unsigned short*)gb;          // 38400 B
    float* outs = (float*)(gb + 38400);                 // 20880 B
    float* xsc  = (float*)(gb + 59280);                 // 2304 B
    float* b1s  = (float*)(smem + 2*GRPB);              // 64 f
    float* b2s  = b1s + 64;                             // 128 f
    float* a0s  = b2s + 128;                            // 160 f (145 used)
    float* vls  = a0s + 160;                            // 160 f (145 used)
    float* accs = (float*)smem;  // 160*ACS*4 = 103,680 B, epilogue only (aliases dead pipeline LDS)

    unsigned short* Mh = mdb;
    unsigned short* Ml = mdb + 160*MDS;
    unsigned short* Dh = mdb + 2*160*MDS;
    unsigned short* ximh = mdb;
    unsigned short* ximl = mdb + 3456;
    unsigned short* a1h  = mdb + 6912;
    unsigned short* a1l  = mdb + 10368;

    const int n = blockIdx.x;
    const int b = n >> 3, h = n & 7;

    const int lane = tid & 63;
    const int wv   = tid >> 6;
    const int frow = lane & 15;
    const int quad = lane >> 4;
    const int wm = wv & 1, wn = wv >> 1;

    if (tid512 < 64)  b1s[tid512] = b1[tid512];
    if (tid512 < 128) b2s[tid512] = b2[tid512];

    const float4* q4 = (const float4*)q + ((long)(b*Lq)*Hq + h)*4;
    const float inv253 = 1.0f / 253.0f;

    // ---- q prefetch: all 4 chunks of this group into registers ----
    float4 rq0, rq1, rq2, rq3;
    if (tid < 140) {
        const int r = tid >> 2, e4 = tid & 3;
        int t;
        t = (0*2 + grp)*32 + r; if (t > 255) t = 255; rq0 = q4[t*32 + e4];
        t = (1*2 + grp)*32 + r; if (t > 255) t = 255; rq1 = q4[t*32 + e4];
        t = (2*2 + grp)*32 + r; if (t > 255) t = 255; rq2 = q4[t*32 + e4];
        t = (3*2 + grp)*32 + r; if (t > 255) t = 255; rq3 = q4[t*32 + e4];
    }

    // ---- conv B-operand fragments: computed once, held in registers ----
    short8 c1bh[2], c1bl[2];
    {
        const int cch = wv*16 + frow;            // conv1 out-channel 0..63
        #pragma unroll
        for (int ks = 0; ks < 2; ++ks) {
            unsigned short hb8[8], lb8[8];
            #pragma unroll
            for (int e = 0; e < 8; ++e) {
                int k = ks*32 + quad*8 + e;      // im2col k 0..63 (48 real)
                float v = (k < 48) ? w1[k*64 + cch] : 0.f;
                unsigned short hbv = f2bf(v);
                hb8[e] = hbv; lb8[e] = f2bf(v - bf2f(hbv));
            }
            c1bh[ks] = *(short8*)hb8; c1bl[ks] = *(short8*)lb8;
        }
    }
    short8 c2bh[2][2], c2bl[2][2];
    #pragma unroll
    for (int nt = 0; nt < 2; ++nt) {
        const int cch = wv*32 + nt*16 + frow;    // conv2 out-channel 0..127
        #pragma unroll
        for (int ks = 0; ks < 2; ++ks) {
            unsigned short hb8[8], lb8[8];
            #pragma unroll
            for (int e = 0; e < 8; ++e) {
                int i = ks*32 + quad*8 + e;      // conv2 in-channel 0..63
                float v = w2[i*128 + cch];
                unsigned short hbv = f2bf(v);
                hb8[e] = hbv; lb8[e] = f2bf(v - bf2f(hbv));
            }
            c2bh[nt][ks] = *(short8*)hb8; c2bl[nt][ks] = *(short8*)lb8;
        }
    }

    floatx4 acc[5][5];
    #pragma unroll
    for (int i = 0; i < 5; ++i)
        #pragma unroll
        for (int j = 0; j < 5; ++j)
            acc[i][j] = (floatx4){0.f, 0.f, 0.f, 0.f};

    #pragma unroll 1
    for (int ci = 0; ci < 4; ++ci) {
        const int c = 2*ci + grp;
        const int t0 = c*32;

        if (tid < 140) {
            float4 qv = (ci == 0) ? rq0 : (ci == 1) ? rq1 : (ci == 2) ? rq2 : rq3;
            ((float4*)xsc)[tid] = qv;
        }
        __syncthreads();   // B1

        for (int idx = tid; idx < 48*8; idx += 256) {
            int r = idx >> 3, g = idx & 7;
            unsigned short hh[8], ll[8];
            if (r <= 32 && g < 6) {
                const float* src = &xsc[r*16 + g*8];
                #pragma unroll
                for (int e = 0; e < 8; ++e) {
                    float v = src[e];
                    unsigned short hbv = f2bf(v);
                    hh[e] = hbv; ll[e] = f2bf(v - bf2f(hbv));
                }
            } else {
                #pragma unroll
                for (int e = 0; e < 8; ++e) { hh[e] = 0; ll[e] = 0; }
            }
            *(ushort8*)&ximh[r*XIS + g*8] = *(ushort8*)hh;
            *(ushort8*)&ximl[r*XIS + g*8] = *(ushort8*)ll;
        }
        __syncthreads();   // B2

        // conv1 MFMA
        {
            short8 ah[3][2], al[3][2];
            #pragma unroll
            for (int mt = 0; mt < 3; ++mt)
                #pragma unroll
                for (int ks = 0; ks < 2; ++ks) {
                    int ar = (mt*16 + frow)*XIS + ks*32 + quad*8;
                    ah[mt][ks] = *(const short8*)&ximh[ar];
                    al[mt][ks] = *(const short8*)&ximl[ar];
                }
            floatx4 acc1[3];
            #pragma unroll
            for (int mt = 0; mt < 3; ++mt) acc1[mt] = (floatx4){0.f,0.f,0.f,0.f};
            #pragma unroll
            for (int mt = 0; mt < 3; ++mt)
                #pragma unroll
                for (int ks = 0; ks < 2; ++ks) {
                    acc1[mt] = __builtin_amdgcn_mfma_f32_16x16x32_bf16(ah[mt][ks], c1bh[ks], acc1[mt], 0,0,0);
                    acc1[mt] = __builtin_amdgcn_mfma_f32_16x16x32_bf16(ah[mt][ks], c1bl[ks], acc1[mt], 0,0,0);
                    acc1[mt] = __builtin_amdgcn_mfma_f32_16x16x32_bf16(al[mt][ks], c1bh[ks], acc1[mt], 0,0,0);
                }
            const int cc = wv*16 + frow;
            const float bias = b1s[cc];
            #pragma unroll
            for (int mt = 0; mt < 3; ++mt)
                #pragma unroll
                for (int e = 0; e < 4; ++e) {
                    int t = mt*16 + quad*4 + e;
                    float v = acc1[mt][e] + bias;
                    unsigned short hbv = f2bf(v);
                    a1h[t*XIS + cc] = hbv;
                    a1l[t*XIS + cc] = f2bf(v - bf2f(hbv));
                }
        }
        __syncthreads();   // B3

        // conv2 MFMA
        {
            short8 ah[3][2], al[3][2];
            #pragma unroll
            for (int mt = 0; mt < 3; ++mt)
                #pragma unroll
                for (int ks = 0; ks < 2; ++ks) {
                    int ar = (mt*16 + frow)*XIS + ks*32 + quad*8;
                    ah[mt][ks] = *(const short8*)&a1h[ar];
                    al[mt][ks] = *(const short8*)&a1l[ar];
                }
            floatx4 acc2[3][2];
            #pragma unroll
            for (int mt = 0; mt < 3; ++mt)
                #pragma unroll
                for (int nt = 0; nt < 2; ++nt)
                    acc2[mt][nt] = (floatx4){0.f,0.f,0.f,0.f};
            #pragma unroll
            for (int mt = 0; mt < 3; ++mt)
                #pragma unroll
                for (int nt = 0; nt < 2; ++nt)
                    #pragma unroll
                    for (int ks = 0; ks < 2; ++ks) {
                        acc2[mt][nt] = __builtin_amdgcn_mfma_f32_16x16x32_bf16(ah[mt][ks], c2bh[nt][ks], acc2[mt][nt], 0,0,0);
                        acc2[mt][nt] = __builtin_amdgcn_mfma_f32_16x16x32_bf16(ah[mt][ks], c2bl[nt][ks], acc2[mt][nt], 0,0,0);
                        acc2[mt][nt] = __builtin_amdgcn_mfma_f32_16x16x32_bf16(al[mt][ks], c2bh[nt][ks], acc2[mt][nt], 0,0,0);
                    }
            #pragma unroll
            for (int mt = 0; mt < 3; ++mt)
                #pragma unroll
                for (int nt = 0; nt < 2; ++nt) {
                    int cc = wv*32 + nt*16 + frow;
                    float bias = b2s[cc];
                    int tb = mt*16 + quad*4;
                    if (tb <= 32) {
                        float4 vv;
                        vv.x = fmaxf(acc2[mt][nt][0] + bias, 0.f);
                        vv.y = fmaxf(acc2[mt][nt][1] + bias, 0.f);
                        vv.z = fmaxf(acc2[mt][nt][2] + bias, 0.f);
                        vv.w = fmaxf(acc2[mt][nt][3] + bias, 0.f);
                        *(float4*)&outs[(17 + cc)*OS3 + tb] = vv;
                    }
                }
        }
        for (int idx = tid; idx < 17*33; idx += 256) {
            int ch = idx / 33, tt = idx - ch*33;
            float val = (ch < 16) ? xsc[(tt+2)*16 + ch] : (float)(t0+tt)*inv253;
            outs[ch*OS3 + tt] = val;
        }
        __syncthreads();   // B4

        // M/D pack: 290 half-row tasks over 256 threads
        for (int task = tid; task < 290; task += 256) {
            int ch = task >> 1, hh2 = task & 1;
            const float* orow = &outs[ch*OS3 + hh2*16];
            float v[17];
            float4 va = *(const float4*)&orow[0];
            float4 vb = *(const float4*)&orow[4];
            float4 vc = *(const float4*)&orow[8];
            float4 vd = *(const float4*)&orow[12];
            v[0]=va.x; v[1]=va.y; v[2]=va.z; v[3]=va.w;
            v[4]=vb.x; v[5]=vb.y; v[6]=vb.z; v[7]=vb.w;
            v[8]=vc.x; v[9]=vc.y; v[10]=vc.z; v[11]=vc.w;
            v[12]=vd.x; v[13]=vd.y; v[14]=vd.z; v[15]=vd.w;
            v[16] = orow[16];
            if (c == 0 && hh2 == 0) a0s[ch] = v[0];      // grp 0, first chunk
            if (c == 7 && hh2 == 1) vls[ch] = v[13];     // grp 1, last chunk (t=253)
            unsigned short mh[16], ml[16], dh[16];
            const int tbase = t0 + hh2*16;
            #pragma unroll
            for (int tl = 0; tl < 16; ++tl) {
                bool valid = (tbase + tl) <= 252;
                float x0 = v[tl], x1 = v[tl+1];
                float d = valid ? (x1 - x0) : 0.f;
                float m = valid ? (0.5f*(x0 + x1)) : 0.f;
                unsigned short hbv = f2bf(m);
                mh[tl] = hbv; ml[tl] = f2bf(m - bf2f(hbv));
                dh[tl] = f2bf(d);
            }
            int mo = ch*MDS + hh2*16;
            *(ushort8*)&Mh[mo]     = *(ushort8*)&mh[0];
            *(ushort8*)&Mh[mo + 8] = *(ushort8*)&mh[8];
            *(ushort8*)&Ml[mo]     = *(ushort8*)&ml[0];
            *(ushort8*)&Ml[mo + 8] = *(ushort8*)&ml[8];
            *(ushort8*)&Dh[mo]     = *(ushort8*)&dh[0];
            *(ushort8*)&Dh[mo + 8] = *(ushort8*)&dh[8];
        }
        __syncthreads();   // B5

        // signature MFMA
        {
            short8 afh[5], afl[5], bfh[5];
            #pragma unroll
            for (int i = 0; i < 5; ++i) {
                int ar = (wm*80 + i*16 + frow)*MDS + quad*8;
                int br = (wn*80 + i*16 + frow)*MDS + quad*8;
                afh[i] = *(const short8*)&Mh[ar];
                afl[i] = *(const short8*)&Ml[ar];
                bfh[i] = *(const short8*)&Dh[br];
            }
            #pragma unroll
            for (int mt = 0; mt < 5; ++mt)
                #pragma unroll
                for (int nt = 0; nt < 5; ++nt) {
                    acc[mt][nt] = __builtin_amdgcn_mfma_f32_16x16x32_bf16(
                        afh[mt], bfh[nt], acc[mt][nt], 0, 0, 0);
                    acc[mt][nt] = __builtin_amdgcn_mfma_f32_16x16x32_bf16(
                        afl[mt], bfh[nt], acc[mt][nt], 0, 0, 0);
                }
        }
    }

    // ----- epilogue -----
    __syncthreads();   // E1: all pipeline LDS dead; a0s/vls valid

    if (grp == 1) {
        #pragma unroll
        for (int mt = 0; mt < 5; ++mt)
            #pragma unroll
            for (int nt = 0; nt < 5; ++nt) {
                int j = wn*80 + nt*16 + frow;
                int ib = wm*80 + mt*16 + quad*4;
                #pragma unroll
                for (int e = 0; e < 4; ++e)
                    accs[(ib + e)*ACS + j] = acc[mt][nt][e];
            }
    }
    __syncthreads();   // E2

    if (grp == 0) {
        // combine + rank-1 correction, staged back into accs (fp32)
        #pragma unroll
        for (int mt = 0; mt < 5; ++mt)
            #pragma unroll
            for (int nt = 0; nt < 5; ++nt) {
                int j = wn*80 + nt*16 + frow;
                int ib = wm*80 + mt*16 + quad*4;
                float s1j = (j < A) ? (vls[j] - a0s[j]) : 0.f;
                #pragma unroll
                for (int e = 0; e < 4; ++e) {
                    int i = ib + e;
                    float a0i = (i < A) ? a0s[i] : 0.f;
                    accs[i*ACS + j] = acc[mt][nt][e] + accs[i*ACS + j] - a0i*s1j;
                }
            }
    }
    __syncthreads();   // E3

    unsigned short* sh = sig_hi + (long)n*KP;
    unsigned short* sl = sig_lo + (long)n*KP;

    if (tid512 < 290) {
        // s2 rows: 2 threads per row, aligned ushort8 bulk + scalar edges
        const int r = tid512 >> 1, hh2 = tid512 & 1;
        const float* row = accs + r*ACS;
        const long g0 = (long)A + (long)r*A;      // ushort offset of row r
        const int s0 = (8 - (int)(g0 & 7)) & 7;   // scalars until 16B-aligned
        if (hh2 == 0) {
            for (int j = 0; j < s0; ++j) {
                float v = row[j];
                unsigned short hbv = f2bf(v);
                sh[g0 + j] = hbv;
                sl[g0 + j] = f2bf(v - bf2f(hbv));
            }
            for (int vb8 = 0; vb8 < 8; ++vb8) {
                int j0 = s0 + vb8*8;
                unsigned short hb8[8], lb8[8];
                #pragma unroll
                for (int e = 0; e < 8; ++e) {
                    float v = row[j0 + e];
                    unsigned short hbv = f2bf(v);
                    hb8[e] = hbv; lb8[e] = f2bf(v - bf2f(hbv));
                }
                *(ushort8*)(sh + g0 + j0) = *(ushort8*)hb8;
                *(ushort8*)(sl + g0 + j0) = *(ushort8*)lb8;
            }
        } else {
            int j0 = s0 + 64;
            for (; j0 + 8 <= A; j0 += 8) {
                unsigned short hb8[8], lb8[8];
                #pragma unroll
                for (int e = 0; e < 8; ++e) {
                    float v = row[j0 + e];
                    unsigned short hbv = f2bf(v);
                    hb8[e] = hbv; lb8[e] = f2bf(v - bf2f(hbv));
                }
                *(ushort8*)(sh + g0 + j0) = *(ushort8*)hb8;
                *(ushort8*)(sl + g0 + j0) = *(ushort8*)lb8;
            }
            for (; j0 < A; ++j0) {
                float v = row[j0];
                unsigned short hbv = f2bf(v);
                sh[g0 + j0] = hbv;
                sl[g0 + j0] = f2bf(v - bf2f(hbv));
            }
        }
    } else if (tid512 < 290 + A) {
        int ch = tid512 - 290;
        float v = vls[ch] - a0s[ch];
        unsigned short hbv = f2bf(v);
        sh[ch] = hbv;
        sl[ch] = f2bf(v - bf2f(hbv));
    } else if (tid512 < 290 + A + (KP - SIG_CH)) {
        int p = tid512 - (290 + A);
        sh[SIG_CH + p] = 0;
        sl[SIG_CH + p] = 0;
    }
}

// ---------------------------------------------------------------------------
// Kernel C: MFMA bf16 split GEMM, 128n x 64o. Split-K deepened: KC=192
// (NSTEP 6), SPLITK=111, grid (4,2,111)=888 blocks -> ~3.5 blocks/CU
// (was 1.9). More resident waves hide the 2-barrier-per-step drain.
// B-operand read DIRECTLY from W (fp32), split to bf16 hi/lo in registers.
// ---------------------------------------------------------------------------
#define SPLITK 111
#define KC 192
#define NSTEP (KC/32)   // 6
#define LDA 40

__global__ __launch_bounds__(256) void gemm_kernel(
    const unsigned short* __restrict__ sig_hi, const unsigned short* __restrict__ sig_lo,
    const float* __restrict__ W,
    float* __restrict__ part)
{
    __shared__ __align__(16) unsigned short Ah[128*LDA];
    __shared__ __align__(16) unsigned short Al[128*LDA];
    __shared__ __align__(16) unsigned short Bh[64*LDA];
    __shared__ __align__(16) unsigned short Bl[64*LDA];

    const int tid = threadIdx.x;
    // XCD-aware bijective swizzle: one z-slice's 8 blocks land on one XCD.
    const int lin  = blockIdx.x + 4*blockIdx.y + 8*blockIdx.z;   // 0..887
    const int lin2 = (lin & 7)*SPLITK + (lin >> 3);              // bijective
    const int z  = lin2 >> 3;
    const int m  = lin2 & 7;
    const int o0 = (m & 3) * 64;
    const int n0 = (m >> 2) * 128;
    const int k0 = z * KC;

    const int lane = tid & 63;
    const int w    = tid >> 6;
    const int wm   = w & 1;          // n half (64 rows)
    const int wn   = w >> 1;         // o half (32 cols)
    const int frow = lane & 15;
    const int quad = lane >> 4;

    const int srowA = tid >> 1;
    const int khA   = (tid & 1) * 16;
    const int oo    = tid & 63;      // B: o-offset (lane-contiguous -> coalesced)
    const int ks8   = tid >> 6;      // B: k-octet 0..3

    const unsigned short* gAh = sig_hi + (long)(n0 + srowA)*KP;
    const unsigned short* gAl = sig_lo + (long)(n0 + srowA)*KP;
    const float*          gB  = W + (o0 + oo);

    ushort8 rah[2], ral[2];
    float wv8[8];
    const ushort8 z8 = {0,0,0,0,0,0,0,0};

    #define GLOAD(s)                                                          \
        {                                                                     \
            int kb = k0 + (s)*32;                                             \
            if (kb < KP) {                                                    \
                rah[0] = *(const ushort8*)(gAh + kb + khA);                   \
                rah[1] = *(const ushort8*)(gAh + kb + khA + 8);               \
                ral[0] = *(const ushort8*)(gAl + kb + khA);                   \
                ral[1] = *(const ushort8*)(gAl + kb + khA + 8);               \
            } else {                                                          \
                rah[0]=z8; rah[1]=z8; ral[0]=z8; ral[1]=z8;                   \
            }                                                                 \
            int kbb = kb + ks8*8;                                             \
            _Pragma("unroll")                                                 \
            for (int j = 0; j < 8; ++j) {                                     \
                int k = kbb + j;                                              \
                wv8[j] = (k < SIG_CH) ? gB[(long)k*OUT] : 0.f;                \
            }                                                                 \
        }

    #define LSTORE()                                                          \
        {                                                                     \
            int oA = srowA*LDA + khA;                                         \
            *(ushort8*)(Ah + oA)     = rah[0];                                \
            *(ushort8*)(Ah + oA + 8) = rah[1];                                \
            *(ushort8*)(Al + oA)     = ral[0];                                \
            *(ushort8*)(Al + oA + 8) = ral[1];                                \
            unsigned short hb8[8], lb8[8];                                    \
            _Pragma("unroll")                                                 \
            for (int j = 0; j < 8; ++j) {                                     \
                unsigned short hbv = f2bf(wv8[j]);                            \
                hb8[j] = hbv; lb8[j] = f2bf(wv8[j] - bf2f(hbv));              \
            }                                                                 \
            int oB = oo*LDA + ks8*8;                                          \
            *(ushort8*)(Bh + oB) = *(ushort8*)hb8;                            \
            *(ushort8*)(Bl + oB) = *(ushort8*)lb8;                            \
        }

    floatx4 acc[4][2];
    #pragma unroll
    for (int i = 0; i < 4; ++i)
        #pragma unroll
        for (int j = 0; j < 2; ++j)
            acc[i][j] = (floatx4){0.f, 0.f, 0.f, 0.f};

    GLOAD(0);
    LSTORE();
    __syncthreads();

    for (int s = 0; s < NSTEP; ++s) {
        if (s < NSTEP-1) GLOAD(s+1);

        short8 afh[4], afl[4], bfh[2], bfl[2];
        const int aoff = (wm*64 + frow)*LDA + quad*8;
        const int boff = (wn*32 + frow)*LDA + quad*8;
        #pragma unroll
        for (int tI = 0; tI < 4; ++tI) {
            afh[tI] = *(const short8*)(Ah + aoff + tI*16*LDA);
            afl[tI] = *(const short8*)(Al + aoff + tI*16*LDA);
        }
        #pragma unroll
        for (int tI = 0; tI < 2; ++tI) {
            bfh[tI] = *(const short8*)(Bh + boff + tI*16*LDA);
            bfl[tI] = *(const short8*)(Bl + boff + tI*16*LDA);
        }
        #pragma unroll
        for (int mt = 0; mt < 4; ++mt)
            #pragma unroll
            for (int nt = 0; nt < 2; ++nt) {
                acc[mt][nt] = __builtin_amdgcn_mfma_f32_16x16x32_bf16(
                    afh[mt], bfh[nt], acc[mt][nt], 0, 0, 0);
                acc[mt][nt] = __builtin_amdgcn_mfma_f32_16x16x32_bf16(
                    afh[mt], bfl[nt], acc[mt][nt], 0, 0, 0);
                acc[mt][nt] = __builtin_amdgcn_mfma_f32_16x16x32_bf16(
                    afl[mt], bfh[nt], acc[mt][nt], 0, 0, 0);
            }
        __syncthreads();
        if (s < NSTEP-1) {
            LSTORE();
            __syncthreads();
        }
    }

    float* pz = part + (long)z * (Nn*OUT);
    #pragma unroll
    for (int mt = 0; mt < 4; ++mt)
        #pragma unroll
        for (int nt = 0; nt < 2; ++nt) {
            int col = o0 + wn*32 + nt*16 + frow;
            int rbase = n0 + wm*64 + mt*16 + quad*4;
            #pragma unroll
            for (int e = 0; e < 4; ++e)
                pz[(long)(rbase + e)*OUT + col] = acc[mt][nt][e];
        }
}

// ---------------------------------------------------------------------------
// Kernel D: out[n][o] = lin_b[o] + sum_z part[z][n][o]
// ---------------------------------------------------------------------------
__global__ __launch_bounds__(256) void reduce_kernel(
    const float* __restrict__ part, const float* __restrict__ lb,
    float* __restrict__ out)
{
    int idx = blockIdx.x * 256 + threadIdx.x;
    float s = lb[idx & 255];
    #pragma unroll 8
    for (int z = 0; z < SPLITK; ++z)
        s += part[(long)z * (Nn*OUT) + idx];
    out[idx] = s;
}

// ---------------------------------------------------------------------------
extern "C" void kernel_launch(void* const* d_in, const int* in_sizes, int n_in,
                              void* d_out, int out_size, void* d_ws, size_t ws_size,
                              hipStream_t stream) {
    const float* q  = (const float*)d_in[0];
    const float* w1 = (const float*)d_in[4];
    const float* b1 = (const float*)d_in[5];
    const float* w2 = (const float*)d_in[6];
    const float* b2 = (const float*)d_in[7];
    const float* lw = (const float*)d_in[8];
    const float* lb = (const float*)d_in[9];
    float* out = (float*)d_out;

    // ws layout (within 59.4 MB proven envelope):
    //   [0]          sig_hi (10,846,208)
    //   [10846208]   sig_lo (10,846,208)
    //   [21692416]   part   (111*65536*4 = 29,097,984)  ends 50,790,400
    char* ws = (char*)d_ws;
    unsigned short* sig_hi  = (unsigned short*)ws;
    unsigned short* sig_lo  = (unsigned short*)(ws + 10846208);
    float*          part    = (float*)(ws + 21692416);

    augsig_kernel<<<Nn, 512, 0, stream>>>(q, b1, b2, w1, w2, sig_hi, sig_lo);
    gemm_kernel<<<dim3(4, 2, SPLITK), 256, 0, stream>>>(sig_hi, sig_lo, lw, part);
    reduce_kernel<<<(Nn*OUT)/256, 256, 0, stream>>>(part, lb, out);
}

// Round 6
// 152.480 us; speedup vs baseline: 1.0137x; 1.0137x over previous
//
#include <hip/hip_runtime.h>
#include <hip/hip_bf16.h>

// Problem constants
#define Bq 32
#define Lq 256
#define Hq 8
#define Eq 16
#define Nn (Bq*Hq)        // 256 sequences
#define T 254             // Lq - 3 + 1
#define A 145             // E + 1 + 128 augmented channels
#define SIG_CH (A + A*A)  // 21170
#define KP 21184          // padded K (mult of 32), bf16 arrays
#define OUT 256

typedef __attribute__((ext_vector_type(8))) short short8;
typedef __attribute__((ext_vector_type(8))) unsigned short ushort8;
typedef __attribute__((ext_vector_type(4))) float floatx4;

static __device__ __forceinline__ unsigned short f2bf(float v) {
    unsigned int u = __float_as_uint(v);
    unsigned int r = (u + 0x7FFFu + ((u >> 16) & 1u)) >> 16;
    return (unsigned short)r;
}
static __device__ __forceinline__ float bf2f(unsigned short b) {
    return __uint_as_float(((unsigned int)b) << 16);
}

// ---------------------------------------------------------------------------
// Kernel AS: FUSED aug+sig (R5 form, unchanged — proven 45.9-46.2 us).
// 512 threads = 2 chunk pipelines; rank-1 a0 correction at fp32 epilogue;
// conv weights in registers; q prefetched to regs then staged via xsc.
// ---------------------------------------------------------------------------
#define MDS 40    // M/D row stride (ushorts)
#define OS3 36    // outs row stride (floats)
#define XIS 72    // xim/a1 row stride (ushorts)
#define GRPB 61600 // per-group LDS bytes
#define ACS 162   // accs row stride (floats)

__global__ __launch_bounds__(512) void augsig_kernel(
    const float* __restrict__ q,
    const float* __restrict__ b1, const float* __restrict__ b2,
    const float* __restrict__ w1, const float* __restrict__ w2,
    unsigned short* __restrict__ sig_hi, unsigned short* __restrict__ sig_lo)
{
    __shared__ __align__(16) char smem[2*GRPB + 256 + 512 + 640 + 640];

    const int tid512 = threadIdx.x;
    const int grp = tid512 >> 8;     // 0 or 1
    const int tid = tid512 & 255;    // local tid within group

    char* gb = smem + grp*GRPB;
    unsigned short* mdb = (unsigned short*)gb;          // 38400 B
    float* outs = (float*)(gb + 38400);                 // 20880 B
    float* xsc  = (float*)(gb + 59280);                 // 2304 B
    float* b1s  = (float*)(smem + 2*GRPB);              // 64 f
    float* b2s  = b1s + 64;                             // 128 f
    float* a0s  = b2s + 128;                            // 160 f (145 used)
    float* vls  = a0s + 160;                            // 160 f (145 used)
    float* accs = (float*)smem;  // epilogue only (aliases dead pipeline LDS)

    unsigned short* Mh = mdb;
    unsigned short* Ml = mdb + 160*MDS;
    unsigned short* Dh = mdb + 2*160*MDS;
    unsigned short* ximh = mdb;
    unsigned short* ximl = mdb + 3456;
    unsigned short* a1h  = mdb + 6912;
    unsigned short* a1l  = mdb + 10368;

    const int n = blockIdx.x;
    const int b = n >> 3, h = n & 7;

    const int lane = tid & 63;
    const int wv   = tid >> 6;
    const int frow = lane & 15;
    const int quad = lane >> 4;
    const int wm = wv & 1, wn = wv >> 1;

    if (tid512 < 64)  b1s[tid512] = b1[tid512];
    if (tid512 < 128) b2s[tid512] = b2[tid512];

    const float4* q4 = (const float4*)q + ((long)(b*Lq)*Hq + h)*4;
    const float inv253 = 1.0f / 253.0f;

    // ---- q prefetch: all 4 chunks of this group into registers ----
    float4 rq0, rq1, rq2, rq3;
    if (tid < 140) {
        const int r = tid >> 2, e4 = tid & 3;
        int t;
        t = (0*2 + grp)*32 + r; if (t > 255) t = 255; rq0 = q4[t*32 + e4];
        t = (1*2 + grp)*32 + r; if (t > 255) t = 255; rq1 = q4[t*32 + e4];
        t = (2*2 + grp)*32 + r; if (t > 255) t = 255; rq2 = q4[t*32 + e4];
        t = (3*2 + grp)*32 + r; if (t > 255) t = 255; rq3 = q4[t*32 + e4];
    }

    // ---- conv B-operand fragments: computed once, held in registers ----
    short8 c1bh[2], c1bl[2];
    {
        const int cch = wv*16 + frow;
        #pragma unroll
        for (int ks = 0; ks < 2; ++ks) {
            unsigned short hb8[8], lb8[8];
            #pragma unroll
            for (int e = 0; e < 8; ++e) {
                int k = ks*32 + quad*8 + e;
                float v = (k < 48) ? w1[k*64 + cch] : 0.f;
                unsigned short hbv = f2bf(v);
                hb8[e] = hbv; lb8[e] = f2bf(v - bf2f(hbv));
            }
            c1bh[ks] = *(short8*)hb8; c1bl[ks] = *(short8*)lb8;
        }
    }
    short8 c2bh[2][2], c2bl[2][2];
    #pragma unroll
    for (int nt = 0; nt < 2; ++nt) {
        const int cch = wv*32 + nt*16 + frow;
        #pragma unroll
        for (int ks = 0; ks < 2; ++ks) {
            unsigned short hb8[8], lb8[8];
            #pragma unroll
            for (int e = 0; e < 8; ++e) {
                int i = ks*32 + quad*8 + e;
                float v = w2[i*128 + cch];
                unsigned short hbv = f2bf(v);
                hb8[e] = hbv; lb8[e] = f2bf(v - bf2f(hbv));
            }
            c2bh[nt][ks] = *(short8*)hb8; c2bl[nt][ks] = *(short8*)lb8;
        }
    }

    floatx4 acc[5][5];
    #pragma unroll
    for (int i = 0; i < 5; ++i)
        #pragma unroll
        for (int j = 0; j < 5; ++j)
            acc[i][j] = (floatx4){0.f, 0.f, 0.f, 0.f};

    #pragma unroll 1
    for (int ci = 0; ci < 4; ++ci) {
        const int c = 2*ci + grp;
        const int t0 = c*32;

        if (tid < 140) {
            float4 qv = (ci == 0) ? rq0 : (ci == 1) ? rq1 : (ci == 2) ? rq2 : rq3;
            ((float4*)xsc)[tid] = qv;
        }
        __syncthreads();   // B1

        for (int idx = tid; idx < 48*8; idx += 256) {
            int r = idx >> 3, g = idx & 7;
            unsigned short hh[8], ll[8];
            if (r <= 32 && g < 6) {
                const float* src = &xsc[r*16 + g*8];
                #pragma unroll
                for (int e = 0; e < 8; ++e) {
                    float v = src[e];
                    unsigned short hbv = f2bf(v);
                    hh[e] = hbv; ll[e] = f2bf(v - bf2f(hbv));
                }
            } else {
                #pragma unroll
                for (int e = 0; e < 8; ++e) { hh[e] = 0; ll[e] = 0; }
            }
            *(ushort8*)&ximh[r*XIS + g*8] = *(ushort8*)hh;
            *(ushort8*)&ximl[r*XIS + g*8] = *(ushort8*)ll;
        }
        __syncthreads();   // B2

        // conv1 MFMA
        {
            short8 ah[3][2], al[3][2];
            #pragma unroll
            for (int mt = 0; mt < 3; ++mt)
                #pragma unroll
                for (int ks = 0; ks < 2; ++ks) {
                    int ar = (mt*16 + frow)*XIS + ks*32 + quad*8;
                    ah[mt][ks] = *(const short8*)&ximh[ar];
                    al[mt][ks] = *(const short8*)&ximl[ar];
                }
            floatx4 acc1[3];
            #pragma unroll
            for (int mt = 0; mt < 3; ++mt) acc1[mt] = (floatx4){0.f,0.f,0.f,0.f};
            #pragma unroll
            for (int mt = 0; mt < 3; ++mt)
                #pragma unroll
                for (int ks = 0; ks < 2; ++ks) {
                    acc1[mt] = __builtin_amdgcn_mfma_f32_16x16x32_bf16(ah[mt][ks], c1bh[ks], acc1[mt], 0,0,0);
                    acc1[mt] = __builtin_amdgcn_mfma_f32_16x16x32_bf16(ah[mt][ks], c1bl[ks], acc1[mt], 0,0,0);
                    acc1[mt] = __builtin_amdgcn_mfma_f32_16x16x32_bf16(al[mt][ks], c1bh[ks], acc1[mt], 0,0,0);
                }
            const int cc = wv*16 + frow;
            const float bias = b1s[cc];
            #pragma unroll
            for (int mt = 0; mt < 3; ++mt)
                #pragma unroll
                for (int e = 0; e < 4; ++e) {
                    int t = mt*16 + quad*4 + e;
                    float v = acc1[mt][e] + bias;
                    unsigned short hbv = f2bf(v);
                    a1h[t*XIS + cc] = hbv;
                    a1l[t*XIS + cc] = f2bf(v - bf2f(hbv));
                }
        }
        __syncthreads();   // B3

        // conv2 MFMA
        {
            short8 ah[3][2], al[3][2];
            #pragma unroll
            for (int mt = 0; mt < 3; ++mt)
                #pragma unroll
                for (int ks = 0; ks < 2; ++ks) {
                    int ar = (mt*16 + frow)*XIS + ks*32 + quad*8;
                    ah[mt][ks] = *(const short8*)&a1h[ar];
                    al[mt][ks] = *(const short8*)&a1l[ar];
                }
            floatx4 acc2[3][2];
            #pragma unroll
            for (int mt = 0; mt < 3; ++mt)
                #pragma unroll
                for (int nt = 0; nt < 2; ++nt)
                    acc2[mt][nt] = (floatx4){0.f,0.f,0.f,0.f};
            #pragma unroll
            for (int mt = 0; mt < 3; ++mt)
                #pragma unroll
                for (int nt = 0; nt < 2; ++nt)
                    #pragma unroll
                    for (int ks = 0; ks < 2; ++ks) {
                        acc2[mt][nt] = __builtin_amdgcn_mfma_f32_16x16x32_bf16(ah[mt][ks], c2bh[nt][ks], acc2[mt][nt], 0,0,0);
                        acc2[mt][nt] = __builtin_amdgcn_mfma_f32_16x16x32_bf16(ah[mt][ks], c2bl[nt][ks], acc2[mt][nt], 0,0,0);
                        acc2[mt][nt] = __builtin_amdgcn_mfma_f32_16x16x32_bf16(al[mt][ks], c2bh[nt][ks], acc2[mt][nt], 0,0,0);
                    }
            #pragma unroll
            for (int mt = 0; mt < 3; ++mt)
                #pragma unroll
                for (int nt = 0; nt < 2; ++nt) {
                    int cc = wv*32 + nt*16 + frow;
                    float bias = b2s[cc];
                    int tb = mt*16 + quad*4;
                    if (tb <= 32) {
                        float4 vv;
                        vv.x = fmaxf(acc2[mt][nt][0] + bias, 0.f);
                        vv.y = fmaxf(acc2[mt][nt][1] + bias, 0.f);
                        vv.z = fmaxf(acc2[mt][nt][2] + bias, 0.f);
                        vv.w = fmaxf(acc2[mt][nt][3] + bias, 0.f);
                        *(float4*)&outs[(17 + cc)*OS3 + tb] = vv;
                    }
                }
        }
        for (int idx = tid; idx < 17*33; idx += 256) {
            int ch = idx / 33, tt = idx - ch*33;
            float val = (ch < 16) ? xsc[(tt+2)*16 + ch] : (float)(t0+tt)*inv253;
            outs[ch*OS3 + tt] = val;
        }
        __syncthreads();   // B4

        // M/D pack: 290 half-row tasks over 256 threads
        for (int task = tid; task < 290; task += 256) {
            int ch = task >> 1, hh2 = task & 1;
            const float* orow = &outs[ch*OS3 + hh2*16];
            float v[17];
            float4 va = *(const float4*)&orow[0];
            float4 vb = *(const float4*)&orow[4];
            float4 vc = *(const float4*)&orow[8];
            float4 vd = *(const float4*)&orow[12];
            v[0]=va.x; v[1]=va.y; v[2]=va.z; v[3]=va.w;
            v[4]=vb.x; v[5]=vb.y; v[6]=vb.z; v[7]=vb.w;
            v[8]=vc.x; v[9]=vc.y; v[10]=vc.z; v[11]=vc.w;
            v[12]=vd.x; v[13]=vd.y; v[14]=vd.z; v[15]=vd.w;
            v[16] = orow[16];
            if (c == 0 && hh2 == 0) a0s[ch] = v[0];
            if (c == 7 && hh2 == 1) vls[ch] = v[13];
            unsigned short mh[16], ml[16], dh[16];
            const int tbase = t0 + hh2*16;
            #pragma unroll
            for (int tl = 0; tl < 16; ++tl) {
                bool valid = (tbase + tl) <= 252;
                float x0 = v[tl], x1 = v[tl+1];
                float d = valid ? (x1 - x0) : 0.f;
                float m = valid ? (0.5f*(x0 + x1)) : 0.f;
                unsigned short hbv = f2bf(m);
                mh[tl] = hbv; ml[tl] = f2bf(m - bf2f(hbv));
                dh[tl] = f2bf(d);
            }
            int mo = ch*MDS + hh2*16;
            *(ushort8*)&Mh[mo]     = *(ushort8*)&mh[0];
            *(ushort8*)&Mh[mo + 8] = *(ushort8*)&mh[8];
            *(ushort8*)&Ml[mo]     = *(ushort8*)&ml[0];
            *(ushort8*)&Ml[mo + 8] = *(ushort8*)&ml[8];
            *(ushort8*)&Dh[mo]     = *(ushort8*)&dh[0];
            *(ushort8*)&Dh[mo + 8] = *(ushort8*)&dh[8];
        }
        __syncthreads();   // B5

        // signature MFMA
        {
            short8 afh[5], afl[5], bfh[5];
            #pragma unroll
            for (int i = 0; i < 5; ++i) {
                int ar = (wm*80 + i*16 + frow)*MDS + quad*8;
                int br = (wn*80 + i*16 + frow)*MDS + quad*8;
                afh[i] = *(const short8*)&Mh[ar];
                afl[i] = *(const short8*)&Ml[ar];
                bfh[i] = *(const short8*)&Dh[br];
            }
            #pragma unroll
            for (int mt = 0; mt < 5; ++mt)
                #pragma unroll
                for (int nt = 0; nt < 5; ++nt) {
                    acc[mt][nt] = __builtin_amdgcn_mfma_f32_16x16x32_bf16(
                        afh[mt], bfh[nt], acc[mt][nt], 0, 0, 0);
                    acc[mt][nt] = __builtin_amdgcn_mfma_f32_16x16x32_bf16(
                        afl[mt], bfh[nt], acc[mt][nt], 0, 0, 0);
                }
        }
    }

    // ----- epilogue -----
    __syncthreads();   // E1

    if (grp == 1) {
        #pragma unroll
        for (int mt = 0; mt < 5; ++mt)
            #pragma unroll
            for (int nt = 0; nt < 5; ++nt) {
                int j = wn*80 + nt*16 + frow;
                int ib = wm*80 + mt*16 + quad*4;
                #pragma unroll
                for (int e = 0; e < 4; ++e)
                    accs[(ib + e)*ACS + j] = acc[mt][nt][e];
            }
    }
    __syncthreads();   // E2

    if (grp == 0) {
        #pragma unroll
        for (int mt = 0; mt < 5; ++mt)
            #pragma unroll
            for (int nt = 0; nt < 5; ++nt) {
                int j = wn*80 + nt*16 + frow;
                int ib = wm*80 + mt*16 + quad*4;
                float s1j = (j < A) ? (vls[j] - a0s[j]) : 0.f;
                #pragma unroll
                for (int e = 0; e < 4; ++e) {
                    int i = ib + e;
                    float a0i = (i < A) ? a0s[i] : 0.f;
                    accs[i*ACS + j] = acc[mt][nt][e] + accs[i*ACS + j] - a0i*s1j;
                }
            }
    }
    __syncthreads();   // E3

    unsigned short* sh = sig_hi + (long)n*KP;
    unsigned short* sl = sig_lo + (long)n*KP;

    if (tid512 < 290) {
        const int r = tid512 >> 1, hh2 = tid512 & 1;
        const float* row = accs + r*ACS;
        const long g0 = (long)A + (long)r*A;
        const int s0 = (8 - (int)(g0 & 7)) & 7;
        if (hh2 == 0) {
            for (int j = 0; j < s0; ++j) {
                float v = row[j];
                unsigned short hbv = f2bf(v);
                sh[g0 + j] = hbv;
                sl[g0 + j] = f2bf(v - bf2f(hbv));
            }
            for (int vb8 = 0; vb8 < 8; ++vb8) {
                int j0 = s0 + vb8*8;
                unsigned short hb8[8], lb8[8];
                #pragma unroll
                for (int e = 0; e < 8; ++e) {
                    float v = row[j0 + e];
                    unsigned short hbv = f2bf(v);
                    hb8[e] = hbv; lb8[e] = f2bf(v - bf2f(hbv));
                }
                *(ushort8*)(sh + g0 + j0) = *(ushort8*)hb8;
                *(ushort8*)(sl + g0 + j0) = *(ushort8*)lb8;
            }
        } else {
            int j0 = s0 + 64;
            for (; j0 + 8 <= A; j0 += 8) {
                unsigned short hb8[8], lb8[8];
                #pragma unroll
                for (int e = 0; e < 8; ++e) {
                    float v = row[j0 + e];
                    unsigned short hbv = f2bf(v);
                    hb8[e] = hbv; lb8[e] = f2bf(v - bf2f(hbv));
                }
                *(ushort8*)(sh + g0 + j0) = *(ushort8*)hb8;
                *(ushort8*)(sl + g0 + j0) = *(ushort8*)lb8;
            }
            for (; j0 < A; ++j0) {
                float v = row[j0];
                unsigned short hbv = f2bf(v);
                sh[g0 + j0] = hbv;
                sl[g0 + j0] = f2bf(v - bf2f(hbv));
            }
        }
    } else if (tid512 < 290 + A) {
        int ch = tid512 - 290;
        float v = vls[ch] - a0s[ch];
        unsigned short hbv = f2bf(v);
        sh[ch] = hbv;
        sl[ch] = f2bf(v - bf2f(hbv));
    } else if (tid512 < 290 + A + (KP - SIG_CH)) {
        int p = tid512 - (290 + A);
        sh[SIG_CH + p] = 0;
        sl[SIG_CH + p] = 0;
    }
}

// ---------------------------------------------------------------------------
// Kernel C: MFMA bf16 split GEMM, 128n x 64o, grid (4,2,61), XCD-swizzled.
// NOW double-buffered LDS (T3-minimum): one barrier per K-step instead of
// two; stage of step s+1 overlaps MFMA of step s. LDS 61.4 KB -> 2 blocks/CU.
// ---------------------------------------------------------------------------
#define SPLITK 61
#define KC 352
#define NSTEP (KC/32)   // 11
#define LDA 40
#define ASZ (128*LDA)
#define BSZ (64*LDA)

__global__ __launch_bounds__(256) void gemm_kernel(
    const unsigned short* __restrict__ sig_hi, const unsigned short* __restrict__ sig_lo,
    const float* __restrict__ W,
    float* __restrict__ part)
{
    __shared__ __align__(16) unsigned short Ah[2*ASZ];
    __shared__ __align__(16) unsigned short Al[2*ASZ];
    __shared__ __align__(16) unsigned short Bh[2*BSZ];
    __shared__ __align__(16) unsigned short Bl[2*BSZ];

    const int tid = threadIdx.x;
    // XCD-aware bijective swizzle: one z-slice's 8 blocks land on one XCD.
    const int lin  = blockIdx.x + 4*blockIdx.y + 8*blockIdx.z;   // 0..487
    const int lin2 = (lin & 7)*SPLITK + (lin >> 3);              // bijective
    const int z  = lin2 >> 3;
    const int m  = lin2 & 7;
    const int o0 = (m & 3) * 64;
    const int n0 = (m >> 2) * 128;
    const int k0 = z * KC;

    const int lane = tid & 63;
    const int w    = tid >> 6;
    const int wm   = w & 1;          // n half (64 rows)
    const int wn   = w >> 1;         // o half (32 cols)
    const int frow = lane & 15;
    const int quad = lane >> 4;

    const int srowA = tid >> 1;
    const int khA   = (tid & 1) * 16;
    const int oo    = tid & 63;      // B: o-offset (lane-contiguous -> coalesced)
    const int ks8   = tid >> 6;      // B: k-octet 0..3

    const unsigned short* gAh = sig_hi + (long)(n0 + srowA)*KP;
    const unsigned short* gAl = sig_lo + (long)(n0 + srowA)*KP;
    const float*          gB  = W + (o0 + oo);

    ushort8 rah[2], ral[2];
    float wv8[8];
    const ushort8 z8 = {0,0,0,0,0,0,0,0};

    #define GLOAD(s)                                                          \
        {                                                                     \
            int kb = k0 + (s)*32;                                             \
            if (kb < KP) {                                                    \
                rah[0] = *(const ushort8*)(gAh + kb + khA);                   \
                rah[1] = *(const ushort8*)(gAh + kb + khA + 8);               \
                ral[0] = *(const ushort8*)(gAl + kb + khA);                   \
                ral[1] = *(const ushort8*)(gAl + kb + khA + 8);               \
            } else {                                                          \
                rah[0]=z8; rah[1]=z8; ral[0]=z8; ral[1]=z8;                   \
            }                                                                 \
            int kbb = kb + ks8*8;                                             \
            _Pragma("unroll")                                                 \
            for (int j = 0; j < 8; ++j) {                                     \
                int k = kbb + j;                                              \
                wv8[j] = (k < SIG_CH) ? gB[(long)k*OUT] : 0.f;                \
            }                                                                 \
        }

    #define LSTORE(bf)                                                        \
        {                                                                     \
            int oA = (bf)*ASZ + srowA*LDA + khA;                              \
            *(ushort8*)(Ah + oA)     = rah[0];                                \
            *(ushort8*)(Ah + oA + 8) = rah[1];                                \
            *(ushort8*)(Al + oA)     = ral[0];                                \
            *(ushort8*)(Al + oA + 8) = ral[1];                                \
            unsigned short hb8[8], lb8[8];                                    \
            _Pragma("unroll")                                                 \
            for (int j = 0; j < 8; ++j) {                                     \
                unsigned short hbv = f2bf(wv8[j]);                            \
                hb8[j] = hbv; lb8[j] = f2bf(wv8[j] - bf2f(hbv));              \
            }                                                                 \
            int oB = (bf)*BSZ + oo*LDA + ks8*8;                               \
            *(ushort8*)(Bh + oB) = *(ushort8*)hb8;                            \
            *(ushort8*)(Bl + oB) = *(ushort8*)lb8;                            \
        }

    floatx4 acc[4][2];
    #pragma unroll
    for (int i = 0; i < 4; ++i)
        #pragma unroll
        for (int j = 0; j < 2; ++j)
            acc[i][j] = (floatx4){0.f, 0.f, 0.f, 0.f};

    GLOAD(0);
    LSTORE(0);
    __syncthreads();

    int cur = 0;
    for (int s = 0; s < NSTEP; ++s) {
        if (s < NSTEP-1) GLOAD(s+1);   // issue next-step loads early

        short8 afh[4], afl[4], bfh[2], bfl[2];
        const int aoff = cur*ASZ + (wm*64 + frow)*LDA + quad*8;
        const int boff = cur*BSZ + (wn*32 + frow)*LDA + quad*8;
        #pragma unroll
        for (int tI = 0; tI < 4; ++tI) {
            afh[tI] = *(const short8*)(Ah + aoff + tI*16*LDA);
            afl[tI] = *(const short8*)(Al + aoff + tI*16*LDA);
        }
        #pragma unroll
        for (int tI = 0; tI < 2; ++tI) {
            bfh[tI] = *(const short8*)(Bh + boff + tI*16*LDA);
            bfl[tI] = *(const short8*)(Bl + boff + tI*16*LDA);
        }
        #pragma unroll
        for (int mt = 0; mt < 4; ++mt)
            #pragma unroll
            for (int nt = 0; nt < 2; ++nt) {
                acc[mt][nt] = __builtin_amdgcn_mfma_f32_16x16x32_bf16(
                    afh[mt], bfh[nt], acc[mt][nt], 0, 0, 0);
                acc[mt][nt] = __builtin_amdgcn_mfma_f32_16x16x32_bf16(
                    afh[mt], bfl[nt], acc[mt][nt], 0, 0, 0);
                acc[mt][nt] = __builtin_amdgcn_mfma_f32_16x16x32_bf16(
                    afl[mt], bfh[nt], acc[mt][nt], 0, 0, 0);
            }
        if (s < NSTEP-1) LSTORE(cur ^ 1);   // other buffer: safe vs. lagging readers
        __syncthreads();                     // single barrier per step
        cur ^= 1;
    }

    float* pz = part + (long)z * (Nn*OUT);
    #pragma unroll
    for (int mt = 0; mt < 4; ++mt)
        #pragma unroll
        for (int nt = 0; nt < 2; ++nt) {
            int col = o0 + wn*32 + nt*16 + frow;
            int rbase = n0 + wm*64 + mt*16 + quad*4;
            #pragma unroll
            for (int e = 0; e < 4; ++e)
                pz[(long)(rbase + e)*OUT + col] = acc[mt][nt][e];
        }
}

// ---------------------------------------------------------------------------
// Kernel D: out[n][o] = lin_b[o] + sum_z part[z][n][o]
// ---------------------------------------------------------------------------
__global__ __launch_bounds__(256) void reduce_kernel(
    const float* __restrict__ part, const float* __restrict__ lb,
    float* __restrict__ out)
{
    int idx = blockIdx.x * 256 + threadIdx.x;
    float s = lb[idx & 255];
    #pragma unroll 8
    for (int z = 0; z < SPLITK; ++z)
        s += part[(long)z * (Nn*OUT) + idx];
    out[idx] = s;
}

// ---------------------------------------------------------------------------
extern "C" void kernel_launch(void* const* d_in, const int* in_sizes, int n_in,
                              void* d_out, int out_size, void* d_ws, size_t ws_size,
                              hipStream_t stream) {
    const float* q  = (const float*)d_in[0];
    const float* w1 = (const float*)d_in[4];
    const float* b1 = (const float*)d_in[5];
    const float* w2 = (const float*)d_in[6];
    const float* b2 = (const float*)d_in[7];
    const float* lw = (const float*)d_in[8];
    const float* lb = (const float*)d_in[9];
    float* out = (float*)d_out;

    // ws layout:
    //   [0]          sig_hi (10,846,208)
    //   [10846208]   sig_lo (10,846,208)
    //   [21692416]   part   (61*65536*4 = 15,990,784)  ends 37,683,200
    char* ws = (char*)d_ws;
    unsigned short* sig_hi  = (unsigned short*)ws;
    unsigned short* sig_lo  = (unsigned short*)(ws + 10846208);
    float*          part    = (float*)(ws + 21692416);

    augsig_kernel<<<Nn, 512, 0, stream>>>(q, b1, b2, w1, w2, sig_hi, sig_lo);
    gemm_kernel<<<dim3(4, 2, SPLITK), 256, 0, stream>>>(sig_hi, sig_lo, lw, part);
    reduce_kernel<<<(Nn*OUT)/256, 256, 0, stream>>>(part, lb, out);
}